// Round 3
// baseline (3408.970 us; speedup 1.0000x reference)
//
#include <hip/hip_runtime.h>
#include <math.h>

#define NN 100000
#define NE 1000000
#define NR 1000
#define DD 100
#define DH 50            // DD/2 : one float2 per lane, lanes 0..49 active
#define OUTC 600
#define EPS 1e-12f
#define CHUNK 8

__device__ inline float wave_sum(float v) {
#pragma unroll
    for (int o = 32; o > 0; o >>= 1) v += __shfl_down(v, o, 64);
    return __shfl(v, 0, 64);
}
// reduce over lanes 0..7 (lanes 8..63 must hold identity); broadcast lane 0
__device__ inline float grp8_max_bcast(float v) {
#pragma unroll
    for (int o = 4; o > 0; o >>= 1) v = fmaxf(v, __shfl_xor(v, o, 64));
    return __shfl(v, 0, 64);
}
__device__ inline float grp8_sum_bcast(float v) {
#pragma unroll
    for (int o = 4; o > 0; o >>= 1) v += __shfl_xor(v, o, 64);
    return __shfl(v, 0, 64);
}

// row_ptr[n] = lower_bound(dst, n); dst sorted ascending. row_ptr[NN] = NE.
__global__ void k_rowptr(const int* __restrict__ dst, int* __restrict__ row_ptr) {
    int n = blockIdx.x * blockDim.x + threadIdx.x;
    if (n > NN) return;
    int lo = 0, hi = NE;
    while (lo < hi) {
        int mid = (lo + hi) >> 1;
        if (dst[mid] < n) lo = mid + 1; else hi = mid;
    }
    row_ptr[n] = lo;
}

// rel_norm[r] = rel_emb[r] / max(||rel_emb[r]||, EPS); one wave per relation
__global__ void k_relnorm(const float* __restrict__ rel_emb, float* __restrict__ rel_norm) {
    int w = (blockIdx.x * blockDim.x + threadIdx.x) >> 6;
    int lane = threadIdx.x & 63;
    if (w >= NR) return;
    const float* r = rel_emb + w * DD;
    float v0 = r[lane];
    float v1 = (lane + 64 < DD) ? r[lane + 64] : 0.f;
    float ss = wave_sum(v0 * v0 + v1 * v1);
    float sc = 1.f / fmaxf(sqrtf(ss), EPS);
    float* o = rel_norm + w * DD;
    o[lane] = v0 * sc;
    if (lane + 64 < DD) o[lane + 64] = v1 * sc;
}

// per-relation dots: rdot[r] = <rel_norm[r], w_r>, rwn[r] = <rel_norm[r], w_n>
__global__ void k_relv(const float* __restrict__ rel_norm, const float* __restrict__ k3d,
                       float* __restrict__ rdot, float* __restrict__ rwn) {
    int w = (blockIdx.x * blockDim.x + threadIdx.x) >> 6;
    int lane = threadIdx.x & 63;
    if (w >= NR) return;
    const float* r = rel_norm + w * DD;
    float r0 = r[lane];
    float r1 = (lane + 64 < DD) ? r[lane + 64] : 0.f;
    float wr1 = 0.f, wn1 = 0.f;
    float wr0 = k3d[2 * DD + lane], wn0 = k3d[DD + lane];
    if (lane + 64 < DD) { wr1 = k3d[2 * DD + lane + 64]; wn1 = k3d[DD + lane + 64]; }
    float rd = wave_sum(r0 * wr0 + r1 * wr1);
    float rn = wave_sum(r0 * wn0 + r1 * wn1);
    if (lane == 0) { rdot[w] = rd; rwn[w] = rn; }
}

// tanh(segment-mean of table[idx[e]]) with 8-deep row prefetch; fused layer-0
// node dots. One wave per node, float2 per lane.
__global__ __launch_bounds__(256) void k_segmean(
        const float* __restrict__ table, const int* __restrict__ idx,
        const int* __restrict__ row_ptr,
        float* __restrict__ F, long long fstride,
        float* __restrict__ outcol, int dup,
        const float* __restrict__ k3d,
        float* __restrict__ sdot, float* __restrict__ ndot) {
    int w = (blockIdx.x * blockDim.x + threadIdx.x) >> 6;
    int lane = threadIdx.x & 63;
    if (w >= NN) return;
    bool act = lane < DH;
    int beg = row_ptr[w], end = row_ptr[w + 1];
    float ax = 0.f, ay = 0.f;
    for (int cb = beg; cb < end; cb += CHUNK) {
        int cnt = min(CHUNK, end - cb);
        int t_l = (lane < cnt) ? idx[cb + lane] : 0;
        float vx[CHUNK], vy[CHUNK];
#pragma unroll
        for (int j = 0; j < CHUNK; ++j) {
            if (j < cnt) {
                int t = __shfl(t_l, j, 64);
                float2 v = act ? ((const float2*)(table + (size_t)t * DD))[lane]
                               : make_float2(0.f, 0.f);
                vx[j] = v.x; vy[j] = v.y;
            }
        }
#pragma unroll
        for (int j = 0; j < CHUNK; ++j)
            if (j < cnt) { ax += vx[j]; ay += vy[j]; }
    }
    float inv = 1.f / fmaxf((float)(end - beg), 1.f);
    float ox = act ? tanhf(ax * inv) : 0.f;
    float oy = act ? tanhf(ay * inv) : 0.f;
    if (act) {
        float2 o2 = make_float2(ox, oy);
        ((float2*)(F + (size_t)w * fstride))[lane] = o2;
        if (dup) ((float2*)(outcol + (size_t)w * OUTC))[lane] = o2;
    }
    float2 wsv = act ? ((const float2*)k3d)[lane] : make_float2(0.f, 0.f);
    float2 wnv = act ? ((const float2*)(k3d + DD))[lane] : make_float2(0.f, 0.f);
    float s  = wave_sum(ox * wsv.x + oy * wsv.y);
    float nn = wave_sum(ox * wnv.x + oy * wnv.y);
    if (lane == 0) { sdot[w] = s; ndot[w] = nn; }
}

// Fused layer: logits + online segment softmax + Householder aggregate.
// One wave per node; 8-deep register prefetch of feats/rel rows; reflected
// rows parked in LDS for the weighted pass. Optionally fuses next-layer dots.
__global__ __launch_bounds__(256) void k_layer(
        const float* __restrict__ F, long long fstride,
        const float* __restrict__ rel_norm,
        const int* __restrict__ src, const int* __restrict__ erel,
        const int* __restrict__ row_ptr,
        const float* __restrict__ sdot, const float* __restrict__ ndot,
        const float* __restrict__ rdot, const float* __restrict__ rwn,
        float* __restrict__ Fnext, long long fnstride,
        float* __restrict__ outcol, int dup,
        const float* __restrict__ k3d_next,
        float* __restrict__ sdot_out, float* __restrict__ ndot_out) {
    __shared__ float2 s_nei[4][CHUNK][DH];
    int wid = threadIdx.x >> 6;
    int lane = threadIdx.x & 63;
    int n = blockIdx.x * 4 + wid;
    if (n >= NN) return;
    bool act = lane < DH;
    int beg = row_ptr[n], end = row_ptr[n + 1];
    float sd = sdot[n];
    float accx = 0.f, accy = 0.f;
    float m_run = -INFINITY, l_run = 0.f;
    for (int cb = beg; cb < end; cb += CHUNK) {
        int cnt = min(CHUNK, end - cb);
        int s_l = 0, r_l = 0;
        float nd_l = 0.f, rd_l = 0.f, rw_l = 0.f;
        if (lane < cnt) {
            s_l = src[cb + lane]; r_l = erel[cb + lane];
            nd_l = ndot[s_l]; rd_l = rdot[r_l]; rw_l = rwn[r_l];
        }
        // phase 1: issue ALL global loads for this chunk (32 loads in flight)
        float fx[CHUNK], fy[CHUNK], rx[CHUNK], ry[CHUNK];
#pragma unroll
        for (int j = 0; j < CHUNK; ++j) {
            if (j < cnt) {
                int s = __shfl(s_l, j, 64);
                int r = __shfl(r_l, j, 64);
                float2 fv = act ? ((const float2*)(F + (size_t)s * fstride))[lane]
                                : make_float2(0.f, 0.f);
                float2 rv = act ? ((const float2*)(rel_norm + (size_t)r * DD))[lane]
                                : make_float2(0.f, 0.f);
                fx[j] = fv.x; fy[j] = fv.y; rx[j] = rv.x; ry[j] = rv.y;
            }
        }
        // phase 2: dots (independent shfl chains), reflect into LDS, logits
        float lg_l = -INFINITY;
#pragma unroll
        for (int j = 0; j < CHUNK; ++j) {
            if (j < cnt) {
                float p = wave_sum(fx[j] * rx[j] + fy[j] * ry[j]);
                float c = 2.f * p;
                if (act) s_nei[wid][j][lane] = make_float2(fx[j] - c * rx[j],
                                                           fy[j] - c * ry[j]);
                float lg = sd + __shfl(nd_l, j, 64) - c * __shfl(rw_l, j, 64)
                           + __shfl(rd_l, j, 64);
                if (lane == j) lg_l = lg;
            }
        }
        // online softmax update over this chunk
        float mc = grp8_max_bcast(lg_l);
        float m_new = fmaxf(m_run, mc);
        float scale = __expf(m_run - m_new);   // exp(-inf)=0 on first chunk
        accx *= scale; accy *= scale; l_run *= scale;
        float w_l = (lane < cnt) ? __expf(lg_l - m_new) : 0.f;
        l_run += grp8_sum_bcast(w_l);
        m_run = m_new;
        // phase 3: weighted accumulate from LDS
#pragma unroll
        for (int j = 0; j < CHUNK; ++j) {
            if (j < cnt) {
                float wgt = __shfl(w_l, j, 64);
                if (act) {
                    float2 nv = s_nei[wid][j][lane];
                    accx += wgt * nv.x; accy += wgt * nv.y;
                }
            }
        }
    }
    float ox = 0.f, oy = 0.f;
    if (end > beg) {
        float inv = 1.f / l_run;
        ox = act ? tanhf(accx * inv) : 0.f;
        oy = act ? tanhf(accy * inv) : 0.f;
    }
    if (act) {
        float2 o2 = make_float2(ox, oy);
        ((float2*)(Fnext + (size_t)n * fnstride))[lane] = o2;
        if (dup) ((float2*)(outcol + (size_t)n * OUTC))[lane] = o2;
    }
    if (k3d_next) {
        float2 wsv = act ? ((const float2*)k3d_next)[lane] : make_float2(0.f, 0.f);
        float2 wnv = act ? ((const float2*)(k3d_next + DD))[lane] : make_float2(0.f, 0.f);
        float s  = wave_sum(ox * wsv.x + oy * wsv.y);
        float nn = wave_sum(ox * wnv.x + oy * wnv.y);
        if (lane == 0) { sdot_out[n] = s; ndot_out[n] = nn; }
    }
}

extern "C" void kernel_launch(void* const* d_in, const int* in_sizes, int n_in,
                              void* d_out, int out_size, void* d_ws, size_t ws_size,
                              hipStream_t stream) {
    const float* ent_emb = (const float*)d_in[0];
    const float* rel_emb = (const float*)d_in[1];
    const float* attn_e  = (const float*)d_in[2];
    const float* attn_r  = (const float*)d_in[3];
    const int*   src     = (const int*)d_in[4];
    const int*   dst     = (const int*)d_in[5];
    const int*   erel    = (const int*)d_in[6];
    float* out = (float*)d_out;

    char* ws = (char*)d_ws;
    size_t off = 0;
    auto alloc = [&](size_t bytes) -> void* {
        void* p = ws + off;
        off = (off + bytes + 255) & ~(size_t)255;
        return p;
    };
    int*   row_ptr  = (int*)alloc((NN + 1) * sizeof(int));
    float* rel_norm = (float*)alloc((size_t)NR * DD * sizeof(float));
    float* sdotA    = (float*)alloc(NN * sizeof(float));
    float* ndotA    = (float*)alloc(NN * sizeof(float));
    float* sdotB    = (float*)alloc(NN * sizeof(float));
    float* ndotB    = (float*)alloc(NN * sizeof(float));
    float* rdot     = (float*)alloc(NR * sizeof(float));
    float* rwn      = (float*)alloc(NR * sizeof(float));
    float* featsA   = (float*)alloc((size_t)NN * DD * sizeof(float));
    float* featsB   = (float*)alloc((size_t)NN * DD * sizeof(float));
    bool compact = (off <= ws_size);

    hipLaunchKernelGGL(k_rowptr, dim3((NN + 256) / 256), dim3(256), 0, stream, dst, row_ptr);
    hipLaunchKernelGGL(k_relnorm, dim3(NR * 64 / 256), dim3(256), 0, stream, rel_emb, rel_norm);

    for (int enc = 0; enc < 2; ++enc) {
        const float* attn  = (enc == 0) ? attn_e : attn_r;
        const float* table = (enc == 0) ? ent_emb : rel_emb;
        const int*   idx   = (enc == 0) ? src : erel;
        int colbase = enc * 300;

        float* F; long long fs;
        if (compact) { F = featsA; fs = DD; }
        else         { F = out + colbase; fs = OUTC; }
        hipLaunchKernelGGL(k_segmean, dim3(NN / 4), dim3(256), 0, stream,
                           table, idx, row_ptr, F, fs,
                           out + colbase, compact ? 1 : 0,
                           attn, sdotA, ndotA);

        for (int l = 0; l < 2; ++l) {
            int colO = colbase + (l + 1) * 100;
            const float* k3d = attn + l * 300;
            const float* k3d_next = (l == 0) ? (attn + 300) : nullptr;
            float* sd_in  = (l == 0) ? sdotA : sdotB;
            float* nd_in  = (l == 0) ? ndotA : ndotB;
            hipLaunchKernelGGL(k_relv, dim3(NR * 64 / 256), dim3(256), 0, stream,
                               rel_norm, k3d, rdot, rwn);
            if (compact) {
                float* Fnx = (l == 0) ? featsB : featsA;  // ping-pong
                hipLaunchKernelGGL(k_layer, dim3(NN / 4), dim3(256), 0, stream,
                                   F, fs, rel_norm, src, erel, row_ptr,
                                   sd_in, nd_in, rdot, rwn,
                                   Fnx, (long long)DD, out + colO, 1,
                                   k3d_next, sdotB, ndotB);
                F = Fnx; fs = DD;
            } else {
                hipLaunchKernelGGL(k_layer, dim3(NN / 4), dim3(256), 0, stream,
                                   F, fs, rel_norm, src, erel, row_ptr,
                                   sd_in, nd_in, rdot, rwn,
                                   out + colO, (long long)OUTC, (float*)nullptr, 0,
                                   k3d_next, sdotB, ndotB);
                F = out + colO; fs = OUTC;
            }
        }
    }
}